// Round 7
// baseline (190.167 us; speedup 1.0000x reference)
//
#include <hip/hip_runtime.h>
#include <cstdint>
#include <cstddef>

// ---------------- types & helpers ----------------
typedef __bf16 bf16x8 __attribute__((ext_vector_type(8)));
typedef float  f32x4  __attribute__((ext_vector_type(4)));
typedef unsigned short ushort8_t __attribute__((ext_vector_type(8)));

__device__ __forceinline__ unsigned short f2bf(float f){
  unsigned u = __builtin_bit_cast(unsigned, f);
  u += 0x7fffu + ((u >> 16) & 1u);
  return (unsigned short)(u >> 16);
}
__device__ __forceinline__ float bf2f(unsigned short s){
  return __builtin_bit_cast(float, ((unsigned)s) << 16);
}

#define MFMA16(a,b,c) __builtin_amdgcn_mfma_f32_16x16x32_bf16((a),(b),(c),0,0,0)

__device__ __forceinline__ void gload16(const void* g, void* lds){
  __builtin_amdgcn_global_load_lds(
      (const __attribute__((address_space(1))) void*)g,
      (__attribute__((address_space(3))) void*)lds, 16, 0, 0);
}

__device__ __forceinline__ void nt_store4(float* p, f32x4 v){
  __builtin_nontemporal_store(v, (f32x4*)p);
}

// ---------------- workspace layout (ushort element offsets) ----------------
#define E_XW    ((size_t)0)                          // word bf16 (2048x1024)
#define E_XS    (E_XW    + (size_t)2048*1024)        // speaker bf16
#define E_WWORD (E_XS    + (size_t)2048*1024)        // [qw_w; kw_w; v_w] (3072x1024)
#define E_WSPK  (E_WWORD + (size_t)3072*1024)        // [qs_w; ks_w] (2048x1024)
#define E_WOUT  (E_WSPK  + (size_t)2048*1024)        // out_w (1024x1024)
#define E_PWORD (E_WOUT  + (size_t)1024*1024)        // proj word (2048x3072): qw|kw|v
#define E_PSPK  (E_PWORD + (size_t)2048*3072)        // proj spk  (2048x2048): qs|ks
#define E_VT    (E_PSPK  + (size_t)2048*2048)        // V^T (32 heads x 64 x 1024)
#define E_CTX   (E_VT    + (size_t)2048*1024)        // ctx bf16 (2048x1024)
#define E_END   (E_CTX   + (size_t)2048*1024)

// ---------------- 0) fp32 -> bf16 conversion + rope tables + bias concat ----------------
__global__ __launch_bounds__(256) void convert_all(
    const float* __restrict__ word, const float* __restrict__ spk,
    const float* __restrict__ qww,  const float* __restrict__ kww,
    const float* __restrict__ vw,   const float* __restrict__ qsw,
    const float* __restrict__ ksw,  const float* __restrict__ outw,
    const float* __restrict__ qwb,  const float* __restrict__ kwb,
    const float* __restrict__ vb,   const float* __restrict__ qsb,
    const float* __restrict__ ksb,
    unsigned short* __restrict__ wsb, float* __restrict__ FB)
{
  int idx = blockIdx.x*256 + threadIdx.x;
  if (idx < 32768){
    int pos = idx >> 5, i = idx & 31;
    float inv = expf((float)(2*i) * -0.14391157f);   // exp(2i * -ln(1e4)/64)
    float ang = (float)pos * inv;
    float sv, cv; sincosf(ang, &sv, &cv);
    FB[5120 + idx]         = sv;   // TS
    FB[5120 + 32768 + idx] = cv;   // TC
  } else if (idx < 33792){
    int i = idx - 32768;
    FB[i] = qwb[i]; FB[1024+i] = kwb[i]; FB[2048+i] = vb[i];
    FB[3072+i] = qsb[i]; FB[3072+1024+i] = ksb[i];
  }

  const size_t total = 2621440;  // float4 chunks
  for (size_t c = (size_t)blockIdx.x*256 + threadIdx.x; c < total;
       c += (size_t)gridDim.x*256){
    const float* src; size_t dst; size_t i;
    if (c < 524288)       { src = word; dst = E_XW; i = c; }
    else if (c < 1048576) { src = spk;  dst = E_XS; i = c - 524288; }
    else {
      size_t t = c - 1048576; int seg = (int)(t >> 18); i = t & 262143;
      switch (seg){
        case 0:  src = qww; dst = E_WWORD;                      break;
        case 1:  src = kww; dst = E_WWORD + (size_t)1048576;    break;
        case 2:  src = vw;  dst = E_WWORD + (size_t)2097152;    break;
        case 3:  src = qsw; dst = E_WSPK;                       break;
        case 4:  src = ksw; dst = E_WSPK  + (size_t)1048576;    break;
        default: src = outw; dst = E_WOUT;                      break;
      }
    }
    float4 v = ((const float4*)src)[i];
    ushort4 o; o.x = f2bf(v.x); o.y = f2bf(v.y); o.z = f2bf(v.z); o.w = f2bf(v.w);
    ((ushort4*)(wsb + dst))[i] = o;
  }
}

// ---------------- 1) bf16 GEMM body, 2-phase double-buffered (T3 minimum recipe) ----------------
// C[m][n] = sum_k A[m][k]*B[n][k] + bias[n].  128 x (NF*32) tile, BK=32.
// Loop: { STAGE(next tile, buf^1); ds_read+MFMA on buf; vmcnt(0); barrier; flip }.
template<int NF>
__device__ __forceinline__ void gemm_body(
    const unsigned short* __restrict__ A, const unsigned short* __restrict__ Bw,
    const float* __restrict__ bias, void* __restrict__ Cv,
    int N, int bid, int out_bf16,
    unsigned short* As, unsigned short* Bs)
{
  const int K = 1024;
  const int BN = NF*32;
  const int nbn = N / BN;
  const int bm = bid / nbn, bn = bid % nbn;
  const int tid = threadIdx.x;
  const int l = tid & 63, w = tid >> 6;
  const int wm = w >> 1, wn = w & 1;
  const int li = l & 15, lg = l >> 4;
  const int ABUF = 128*32;
  const int BBUF = BN*32;

  f32x4 acc[4][NF];
  #pragma unroll
  for (int a = 0; a < 4; a++)
    #pragma unroll
    for (int b = 0; b < NF; b++) acc[a][b] = (f32x4){0.f,0.f,0.f,0.f};

  const size_t aBase = (size_t)(bm*128) * K;
  const size_t bBase = (size_t)(bn*BN) * K;

  // prologue: stage tile 0 into buf 0
  #pragma unroll
  for (int j = 0; j < 2; j++){
    int c = (w*2 + j)*64 + l;
    gload16(A + aBase + (size_t)(c >> 2)*K + (c & 3)*8, &As[(w*2+j)*512]);
  }
  #pragma unroll
  for (int j = 0; j < NF/2; j++){
    int c = (w*(NF/2) + j)*64 + l;
    gload16(Bw + bBase + (size_t)(c >> 2)*K + (c & 3)*8, &Bs[(w*(NF/2)+j)*512]);
  }
  asm volatile("s_waitcnt vmcnt(0)" ::: "memory");
  __syncthreads();

  int cur = 0;
  for (int kt = 0; kt < K; kt += 32){
    // issue next-tile staging first (overlaps with compute below)
    if (kt + 32 < K){
      int nb = cur ^ 1;
      #pragma unroll
      for (int j = 0; j < 2; j++){
        int c = (w*2 + j)*64 + l;
        gload16(A + aBase + (size_t)(c >> 2)*K + kt + 32 + (c & 3)*8,
                &As[nb*ABUF + (w*2+j)*512]);
      }
      #pragma unroll
      for (int j = 0; j < NF/2; j++){
        int c = (w*(NF/2) + j)*64 + l;
        gload16(Bw + bBase + (size_t)(c >> 2)*K + kt + 32 + (c & 3)*8,
                &Bs[nb*BBUF + (w*(NF/2)+j)*512]);
      }
    }
    // compute current buffer
    bf16x8 af[4], bfr[NF];
    const int ko = lg * 8;
    #pragma unroll
    for (int fm = 0; fm < 4; fm++)
      af[fm] = *(const bf16x8*)&As[cur*ABUF + (wm*64 + fm*16 + li)*32 + ko];
    #pragma unroll
    for (int fn = 0; fn < NF; fn++)
      bfr[fn] = *(const bf16x8*)&Bs[cur*BBUF + (wn*(NF*16) + fn*16 + li)*32 + ko];
    #pragma unroll
    for (int fm = 0; fm < 4; fm++)
      #pragma unroll
      for (int fn = 0; fn < NF; fn++)
        acc[fm][fn] = MFMA16(af[fm], bfr[fn], acc[fm][fn]);
    // publish staged tile
    asm volatile("s_waitcnt vmcnt(0)" ::: "memory");
    __syncthreads();
    cur ^= 1;
  }

  #pragma unroll
  for (int fm = 0; fm < 4; fm++){
    int m0 = bm*128 + wm*64 + fm*16 + lg*4;
    #pragma unroll
    for (int fn = 0; fn < NF; fn++){
      int n = bn*BN + wn*(NF*16) + fn*16 + li;
      float bv = bias[n];
      #pragma unroll
      for (int r = 0; r < 4; r++){
        float v = acc[fm][fn][r] + bv;
        if (out_bf16) ((unsigned short*)Cv)[(size_t)(m0+r)*N + n] = f2bf(v);
        else          ((float*)Cv)[(size_t)(m0+r)*N + n] = v;
      }
    }
  }
}

// word (384 tiles, N=3072) + speaker (256 tiles, N=2048) fused: 640 blocks
__global__ __launch_bounds__(256) void gemm_qkv(
    const unsigned short* __restrict__ XW, const unsigned short* __restrict__ WWORD,
    const unsigned short* __restrict__ XS, const unsigned short* __restrict__ WSPK,
    const float* __restrict__ FB,
    unsigned short* __restrict__ PWORD, unsigned short* __restrict__ PSPK)
{
  __shared__ unsigned short As[2*128*32];
  __shared__ unsigned short Bs[2*128*32];
  int bid = blockIdx.x;
  if (bid < 384)
    gemm_body<4>(XW, WWORD, FB,        PWORD, 3072, bid,       1, As, Bs);
  else
    gemm_body<4>(XS, WSPK,  FB + 3072, PSPK,  2048, bid - 384, 1, As, Bs);
}

// output projection: 128x64 tiles, 256 blocks
__global__ __launch_bounds__(256) void gemm_out(
    const unsigned short* __restrict__ CTX, const unsigned short* __restrict__ WOUT,
    const float* __restrict__ outb, float* __restrict__ outp)
{
  __shared__ unsigned short As[2*128*32];
  __shared__ unsigned short Bs[2*64*32];
  gemm_body<2>(CTX, WOUT, outb, outp, 1024, blockIdx.x, 0, As, Bs);
}

// ---------------- 2) rotary+LN (vectorized, table) + V transpose, one dispatch ----------------
__global__ __launch_bounds__(256) void postproc(
    unsigned short* __restrict__ Pw, unsigned short* __restrict__ Ps,
    const float* __restrict__ gamma, const float* __restrict__ beta,
    const float* __restrict__ TS, const float* __restrict__ TC,
    unsigned short* __restrict__ VT)
{
  __shared__ float lds[2320];
  int bx = blockIdx.x;
  int t = threadIdx.x;
  if (bx < 4096){
    int sec = bx & 3, rp = bx >> 2;
    int half = t >> 7, c = t & 127;
    int row = rp*2 + half;
    int seg = c >> 3, j = c & 7;
    unsigned short* p;
    if      (sec == 0) p = Pw + (size_t)row*3072 +        seg*64;
    else if (sec == 1) p = Pw + (size_t)row*3072 + 1024 + seg*64;
    else if (sec == 2) p = Ps + (size_t)row*2048 +        seg*64;
    else               p = Ps + (size_t)row*2048 + 1024 + seg*64;
    int pos = row & 1023;
    int sl  = half*16 + seg;

    ushort8_t xv = *(const ushort8_t*)(p + j*8);
    float4 sv = *(const float4*)&TS[pos*32 + j*4];
    float4 cv = *(const float4*)&TC[pos*32 + j*4];
    float ss[4] = {sv.x, sv.y, sv.z, sv.w};
    float cc[4] = {cv.x, cv.y, cv.z, cv.w};
    float y1[4], y2[4];
    #pragma unroll
    for (int k = 0; k < 4; k++){
      float x0 = bf2f(xv[2*k]), x1 = bf2f(xv[2*k+1]);
      y1[k] = x0*cc[k] - x1*ss[k];
      y2[k] = x0*ss[k] + x1*cc[k];
    }
    *(float4*)&lds[sl*68 + j*4]      = (float4){y1[0], y1[1], y1[2], y1[3]};
    *(float4*)&lds[sl*68 + 32 + j*4] = (float4){y2[0], y2[1], y2[2], y2[3]};
    __syncthreads();

    float4 a0 = *(const float4*)&lds[sl*68 + j*8];
    float4 a1 = *(const float4*)&lds[sl*68 + j*8 + 4];
    float v[8] = {a0.x, a0.y, a0.z, a0.w, a1.x, a1.y, a1.z, a1.w};
    float s = 0.f;
    #pragma unroll
    for (int k = 0; k < 8; k++) s += v[k];
    #pragma unroll
    for (int o = 1; o < 8; o <<= 1) s += __shfl_xor(s, o);
    float mu = s * (1.f/64.f);
    float sq = 0.f;
    #pragma unroll
    for (int k = 0; k < 8; k++){ float d = v[k] - mu; sq += d*d; }
    #pragma unroll
    for (int o = 1; o < 8; o <<= 1) sq += __shfl_xor(sq, o);
    float rs = rsqrtf(sq * (1.f/64.f) + 1e-5f);
    float4 g0 = *(const float4*)&gamma[j*8], g1 = *(const float4*)&gamma[j*8+4];
    float4 b0 = *(const float4*)&beta[j*8],  b1 = *(const float4*)&beta[j*8+4];
    float gg[8] = {g0.x,g0.y,g0.z,g0.w,g1.x,g1.y,g1.z,g1.w};
    float bb[8] = {b0.x,b0.y,b0.z,b0.w,b1.x,b1.y,b1.z,b1.w};
    ushort8_t o8;
    #pragma unroll
    for (int k = 0; k < 8; k++) o8[k] = f2bf((v[k]-mu)*rs*gg[k] + bb[k]);
    *(ushort8_t*)(p + j*8) = o8;
  } else {
    unsigned short* tp = (unsigned short*)lds;   // 64 x 72
    int bid2 = bx - 4096;
    int bh = bid2 >> 4, lt = bid2 & 15;
    int b = bh >> 4, h = bh & 15;
    #pragma unroll
    for (int i = 0; i < 2; i++){
      int cc2 = t + i*256;
      int row = cc2 >> 3, co = (cc2 & 7)*8;
      const unsigned short* src = Pw + (size_t)(b*1024 + lt*64 + row)*3072 + 2048 + h*64 + co;
      *(uint4*)&tp[row*72 + co] = *(const uint4*)src;
    }
    __syncthreads();
    int d = t >> 2, jb = (t & 3)*16;
    unsigned short o[16];
    #pragma unroll
    for (int j = 0; j < 16; j++) o[j] = tp[(jb + j)*72 + d];
    unsigned short* dst = VT + ((size_t)bh*64 + d)*1024 + lt*64 + jb;
    *(uint4*)dst       = *(uint4*)&o[0];
    *(uint4*)(dst + 8) = *(uint4*)&o[8];
  }
}

// ---------------- 3) fused attention, LDS-staged, fixed-max softmax ----------------
// grid 256 = (b, h, qq); 8 waves. Waves 0-3: q-band qt=qq, waves 4-7: qt=15-qq.
__global__ __launch_bounds__(512) void attn_fused(
    const unsigned short* __restrict__ Pw, const unsigned short* __restrict__ Ps,
    const unsigned short* __restrict__ VTg,
    float* __restrict__ attn, unsigned short* __restrict__ Ctx)
{
  // LDS: KW[2][64][72] | KS[2][64][72] | VT[2][64][72] | PT[8][16][72]
  __shared__ unsigned short SL[36864];   // 73728 B

  int bx = blockIdx.x;
  int b = bx >> 7, rem = bx & 127, h = rem >> 3, qq = rem & 7;
  int maxkt = 15 - qq;
  int tid = threadIdx.x;
  int w = tid >> 6, l = tid & 63;
  int g = w >> 2, wsub = w & 3;
  int qt = g ? maxkt : qq;
  int lg = l >> 4, li = l & 15;
  int q0 = qt*64 + wsub*16;
  int bh = b*16 + h;

  int srow = tid >> 3, scb = tid & 7;      // staging: row 0..63, 16B chunk 0..7
  const unsigned short* gKW = Pw + (size_t)(b*1024)*3072 + 1024 + h*64;
  const unsigned short* gKS = Ps + (size_t)(b*1024)*2048 + 1024 + h*64;
  const unsigned short* gVT = VTg + (size_t)bh*64*1024;
  unsigned short* pt = SL + 27648 + w*1152;

  // Q fragments
  bf16x8 aqw[2], aqs[2];
  {
    int q = q0 + li;
    const unsigned short* pqw = Pw + (size_t)(b*1024 + q)*3072 + h*64 + lg*8;
    const unsigned short* pqs = Ps + (size_t)(b*1024 + q)*2048 + h*64 + lg*8;
    aqw[0] = *(const bf16x8*)pqw;  aqw[1] = *(const bf16x8*)(pqw + 32);
    aqs[0] = *(const bf16x8*)pqs;  aqs[1] = *(const bf16x8*)(pqs + 32);
  }
  const float rscale = 0.08838834764831845f;   // 1/sqrt(2*HD)

  uint4 rkw, rks, rvt;

  // ---- sweep 1: row sums ----
  float ps4[4] = {0.f, 0.f, 0.f, 0.f};
  rkw = *(const uint4*)(gKW + (size_t)srow*3072 + scb*8);
  rks = *(const uint4*)(gKS + (size_t)srow*2048 + scb*8);
  *(uint4*)(SL +        srow*72 + scb*8) = rkw;
  *(uint4*)(SL + 9216 + srow*72 + scb*8) = rks;

  for (int kt = 0; kt <= maxkt; ++kt){
    int buf = kt & 1;
    if (kt < maxkt){
      rkw = *(const uint4*)(gKW + (size_t)((kt+1)*64 + srow)*3072 + scb*8);
      rks = *(const uint4*)(gKS + (size_t)((kt+1)*64 + srow)*2048 + scb*8);
    }
    __syncthreads();
    if (kt <= qt){
      const unsigned short* KWt = SL +        buf*4608;
      const unsigned short* KSt = SL + 9216 + buf*4608;
      f32x4 s[4];
      #pragma unroll
      for (int fn = 0; fn < 4; fn++){
        s[fn] = (f32x4){0.f,0.f,0.f,0.f};
        int rr = (fn*16 + li)*72;
        bf16x8 k0 = *(const bf16x8*)(KWt + rr + lg*8);
        bf16x8 k1 = *(const bf16x8*)(KWt + rr + 32 + lg*8);
        bf16x8 k2 = *(const bf16x8*)(KSt + rr + lg*8);
        bf16x8 k3 = *(const bf16x8*)(KSt + rr + 32 + lg*8);
        s[fn] = MFMA16(aqw[0], k0, s[fn]);
        s[fn] = MFMA16(aqw[1], k1, s[fn]);
        s[fn] = MFMA16(aqs[0], k2, s[fn]);
        s[fn] = MFMA16(aqs[1], k3, s[fn]);
      }
      #pragma unroll
      for (int r = 0; r < 4; r++){
        int q = q0 + lg*4 + r;
        #pragma unroll
        for (int fn = 0; fn < 4; fn++){
          int k = kt*64 + fn*16 + li;
          float e = __expf(s[fn][r] * rscale);
          ps4[r] += (k <= q) ? e : 0.f;
        }
      }
    }
    if (kt < maxkt){
      int nb = buf ^ 1;
      *(uint4*)(SL +        nb*4608 + srow*72 + scb*8) = rkw;
      *(uint4*)(SL + 9216 + nb*4608 + srow*72 + scb*8) = rks;
    }
  }
  #pragma unroll
  for (int r = 0; r < 4; r++){
    #pragma unroll
    for (int o = 1; o < 16; o <<= 1) ps4[r] += __shfl_xor(ps4[r], o);
  }
  float rinv[4];
  #pragma unroll
  for (int r = 0; r < 4; r++) rinv[r] = 1.f / ps4[r];

  // ---- sweep 2: recompute, normalize, write attn, PV ----
  __syncthreads();   // sweep1 reads done before re-staging buf0
  rkw = *(const uint4*)(gKW + (size_t)srow*3072 + scb*8);
  rks = *(const uint4*)(gKS + (size_t)srow*2048 + scb*8);
  rvt = *(const uint4*)(gVT + (size_t)srow*1024 + scb*8);
  *(uint4*)(SL +         srow*72 + scb*8) = rkw;
  *(uint4*)(SL +  9216 + srow*72 + scb*8) = rks;
  *(uint4*)(SL + 18432 + srow*72 + scb*8) = rvt;

  f32x4 c[4];
  #pragma unroll
  for (int fn = 0; fn < 4; fn++) c[fn] = (f32x4){0.f,0.f,0.f,0.f};

  for (int kt = 0; kt < 16; ++kt){
    int buf = kt & 1;
    if (kt < maxkt){
      rkw = *(const uint4*)(gKW + (size_t)((kt+1)*64 + srow)*3072 + scb*8);
      rks = *(const uint4*)(gKS + (size_t)((kt+1)*64 + srow)*2048 + scb*8);
      rvt = *(const uint4*)(gVT + (size_t)srow*1024 + (kt+1)*64 + scb*8);
    }
    __syncthreads();
    float* abase = attn + ((size_t)bh*1024 + q0 + li)*1024 + kt*64;
    if (kt <= qt){
      const unsigned short* KWt = SL +         buf*4608;
      const unsigned short* KSt = SL +  9216 + buf*4608;
      const unsigned short* VTt = SL + 18432 + buf*4608;
      f32x4 s[4];
      #pragma unroll
      for (int fn = 0; fn < 4; fn++){
        s[fn] = (f32x4){0.f,0.f,0.f,0.f};
        int rr = (fn*16 + li)*72;
        bf16x8 k0 = *(const bf16x8*)(KWt + rr + lg*8);
        bf16x8 k1 = *(const bf16x8*)(KWt + rr + 32 + lg*8);
        bf16x8 k2 = *(const bf16x8*)(KSt + rr + lg*8);
        bf16x8 k3 = *(const bf16x8*)(KSt + rr + 32 + lg*8);
        s[fn] = MFMA16(aqw[0], k0, s[fn]);
        s[fn] = MFMA16(aqw[1], k1, s[fn]);
        s[fn] = MFMA16(aqs[0], k2, s[fn]);
        s[fn] = MFMA16(aqs[1], k3, s[fn]);
      }
      #pragma unroll
      for (int fn = 0; fn < 4; fn++){
        #pragma unroll
        for (int r = 0; r < 4; r++){
          int k = kt*64 + fn*16 + li;
          int q = q0 + lg*4 + r;
          float pp = (k <= q) ? __expf(s[fn][r] * rscale) * rinv[r] : 0.f;
          pt[(lg*4 + r)*72 + fn*16 + li] = f2bf(pp);
        }
      }
      asm volatile("s_waitcnt lgkmcnt(0)" ::: "memory");
      __builtin_amdgcn_sched_barrier(0);
      bf16x8 af0 = *(const bf16x8*)(pt + li*72 + lg*8);
      bf16x8 af1 = *(const bf16x8*)(pt + li*72 + 32 + lg*8);
      ushort8_t u0 = __builtin_bit_cast(ushort8_t, af0);
      ushort8_t u1 = __builtin_bit_cast(ushort8_t, af1);
      f32x4 w0 = {bf2f(u0[0]),bf2f(u0[1]),bf2f(u0[2]),bf2f(u0[3])};
      f32x4 w1 = {bf2f(u0[4]),bf2f(u0[5]),bf2f(u0[6]),bf2f(u0[7])};
      f32x4 w2 = {bf2f(u1[0]),bf2f(u1[1]),bf2f(u1[2]),bf2f(u1[3])};
      f32x4 w3 = {bf2f(u1[4]),bf2f(u1[5]),bf2f(u1[6]),bf2f(u1[7])};
      nt_store4(abase + lg*8,          w0);
      nt_store4(abase + lg*8 + 4,      w1);
      nt_store4(abase + 32 + lg*8,     w2);
      nt_store4(abase + 32 + lg*8 + 4, w3);
      #pragma unroll
      for (int fn = 0; fn < 4; fn++){
        int rr = (fn*16 + li)*72;
        bf16x8 v0 = *(const bf16x8*)(VTt + rr + lg*8);
        bf16x8 v1 = *(const bf16x8*)(VTt + rr + 32 + lg*8);
        c[fn] = MFMA16(af0, v0, c[fn]);
        c[fn] = MFMA16(af1, v1, c[fn]);
      }
    } else {
      f32x4 z = {0.f, 0.f, 0.f, 0.f};
      nt_store4(abase + lg*8,          z);
      nt_store4(abase + lg*8 + 4,      z);
      nt_store4(abase + 32 + lg*8,     z);
      nt_store4(abase + 32 + lg*8 + 4, z);
    }
    if (kt < maxkt){
      int nb = buf ^ 1;
      *(uint4*)(SL +         nb*4608 + srow*72 + scb*8) = rkw;
      *(uint4*)(SL +  9216 + nb*4608 + srow*72 + scb*8) = rks;
      *(uint4*)(SL + 18432 + nb*4608 + srow*72 + scb*8) = rvt;
    }
  }

  // ctx write: D layout row=(l>>4)*4+r, col=l&15  (re-read by gemm_out -> keep cached)
  #pragma unroll
  for (int fn = 0; fn < 4; fn++){
    #pragma unroll
    for (int r = 0; r < 4; r++){
      int q = q0 + lg*4 + r;
      int d = fn*16 + li;
      Ctx[(size_t)(b*1024 + q)*1024 + h*64 + d] = f2bf(c[fn][r]);
    }
  }
}

// ---------------- host launch ----------------
extern "C" void kernel_launch(void* const* d_in, const int* in_sizes, int n_in,
                              void* d_out, int out_size, void* d_ws, size_t ws_size,
                              hipStream_t stream)
{
  (void)in_sizes; (void)n_in; (void)out_size; (void)ws_size;
  const float* word = (const float*)d_in[0];
  const float* spk  = (const float*)d_in[1];
  const float* qww  = (const float*)d_in[3];
  const float* qwb  = (const float*)d_in[4];
  const float* kww  = (const float*)d_in[5];
  const float* kwb  = (const float*)d_in[6];
  const float* qsw  = (const float*)d_in[7];
  const float* qsb  = (const float*)d_in[8];
  const float* ksw  = (const float*)d_in[9];
  const float* ksb  = (const float*)d_in[10];
  const float* vw   = (const float*)d_in[11];
  const float* vb   = (const float*)d_in[12];
  const float* outw = (const float*)d_in[13];
  const float* outb = (const float*)d_in[14];
  const float* gamma= (const float*)d_in[15];
  const float* beta = (const float*)d_in[16];

  unsigned short* U = (unsigned short*)d_ws;
  unsigned short* XW    = U + E_XW;
  unsigned short* XS    = U + E_XS;
  unsigned short* WWORD = U + E_WWORD;
  unsigned short* WSPK  = U + E_WSPK;
  unsigned short* WOUT  = U + E_WOUT;
  unsigned short* PWORD = U + E_PWORD;
  unsigned short* PSPK  = U + E_PSPK;
  unsigned short* VT    = U + E_VT;
  unsigned short* CTX   = U + E_CTX;
  float* FB = (float*)(U + E_END);
  float* TS = FB + 5120;
  float* TC = TS + 32768;

  float* outp = (float*)d_out;
  float* attn = outp + (size_t)2*1024*1024;

  convert_all<<<4096, 256, 0, stream>>>(word, spk, qww, kww, vw, qsw, ksw, outw,
                                        qwb, kwb, vb, qsb, ksb, U, FB);
  gemm_qkv<<<640, 256, 0, stream>>>(XW, WWORD, XS, WSPK, FB, PWORD, PSPK);
  postproc<<<4608, 256, 0, stream>>>(PWORD, PSPK, gamma, beta, TS, TC, VT);
  attn_fused<<<256, 512, 0, stream>>>(PWORD, PSPK, VT, attn, CTX);
  gemm_out<<<256, 256, 0, stream>>>(CTX, WOUT, outb, outp);
}

// Round 8
// 137.943 us; speedup vs baseline: 1.3786x; 1.3786x over previous
//
#include <hip/hip_runtime.h>
#include <cstdint>
#include <cstddef>

// ---------------- types & helpers ----------------
typedef __bf16 bf16x8 __attribute__((ext_vector_type(8)));
typedef float  f32x4  __attribute__((ext_vector_type(4)));
typedef unsigned short ushort8_t __attribute__((ext_vector_type(8)));

__device__ __forceinline__ unsigned short f2bf(float f){
  unsigned u = __builtin_bit_cast(unsigned, f);
  u += 0x7fffu + ((u >> 16) & 1u);
  return (unsigned short)(u >> 16);
}
__device__ __forceinline__ float bf2f(unsigned short s){
  return __builtin_bit_cast(float, ((unsigned)s) << 16);
}

#define MFMA16(a,b,c) __builtin_amdgcn_mfma_f32_16x16x32_bf16((a),(b),(c),0,0,0)

__device__ __forceinline__ void gload16(const void* g, void* lds){
  __builtin_amdgcn_global_load_lds(
      (const __attribute__((address_space(1))) void*)g,
      (__attribute__((address_space(3))) void*)lds, 16, 0, 0);
}

// ---------------- workspace layout (ushort element offsets) ----------------
#define E_XW    ((size_t)0)                          // word bf16 (2048x1024)
#define E_XS    (E_XW    + (size_t)2048*1024)        // speaker bf16
#define E_WWORD (E_XS    + (size_t)2048*1024)        // [qw_w; kw_w; v_w] (3072x1024)
#define E_WSPK  (E_WWORD + (size_t)3072*1024)        // [qs_w; ks_w] (2048x1024)
#define E_WOUT  (E_WSPK  + (size_t)2048*1024)        // out_w (1024x1024)
#define E_PWORD (E_WOUT  + (size_t)1024*1024)        // proj word (2048x3072): qw|kw|v
#define E_PSPK  (E_PWORD + (size_t)2048*3072)        // proj spk  (2048x2048): qs|ks
#define E_VT    (E_PSPK  + (size_t)2048*2048)        // V^T (32 heads x 64 x 1024)
#define E_CTX   (E_VT    + (size_t)2048*1024)        // ctx bf16 (2048x1024)
#define E_END   (E_CTX   + (size_t)2048*1024)

// ---------------- 0) fp32 -> bf16 conversion + rope tables + bias concat ----------------
__global__ __launch_bounds__(256) void convert_all(
    const float* __restrict__ word, const float* __restrict__ spk,
    const float* __restrict__ qww,  const float* __restrict__ kww,
    const float* __restrict__ vw,   const float* __restrict__ qsw,
    const float* __restrict__ ksw,  const float* __restrict__ outw,
    const float* __restrict__ qwb,  const float* __restrict__ kwb,
    const float* __restrict__ vb,   const float* __restrict__ qsb,
    const float* __restrict__ ksb,
    unsigned short* __restrict__ wsb, float* __restrict__ FB)
{
  int idx = blockIdx.x*256 + threadIdx.x;
  if (idx < 32768){
    int pos = idx >> 5, i = idx & 31;
    float inv = expf((float)(2*i) * -0.14391157f);   // exp(2i * -ln(1e4)/64)
    float ang = (float)pos * inv;
    float sv, cv; sincosf(ang, &sv, &cv);
    FB[5120 + idx]         = sv;   // TS
    FB[5120 + 32768 + idx] = cv;   // TC
  } else if (idx < 33792){
    int i = idx - 32768;
    FB[i] = qwb[i]; FB[1024+i] = kwb[i]; FB[2048+i] = vb[i];
    FB[3072+i] = qsb[i]; FB[3072+1024+i] = ksb[i];
  }

  const size_t total = 2621440;  // float4 chunks
  for (size_t c = (size_t)blockIdx.x*256 + threadIdx.x; c < total;
       c += (size_t)gridDim.x*256){
    const float* src; size_t dst; size_t i;
    if (c < 524288)       { src = word; dst = E_XW; i = c; }
    else if (c < 1048576) { src = spk;  dst = E_XS; i = c - 524288; }
    else {
      size_t t = c - 1048576; int seg = (int)(t >> 18); i = t & 262143;
      switch (seg){
        case 0:  src = qww; dst = E_WWORD;                      break;
        case 1:  src = kww; dst = E_WWORD + (size_t)1048576;    break;
        case 2:  src = vw;  dst = E_WWORD + (size_t)2097152;    break;
        case 3:  src = qsw; dst = E_WSPK;                       break;
        case 4:  src = ksw; dst = E_WSPK  + (size_t)1048576;    break;
        default: src = outw; dst = E_WOUT;                      break;
      }
    }
    float4 v = ((const float4*)src)[i];
    ushort4 o; o.x = f2bf(v.x); o.y = f2bf(v.y); o.z = f2bf(v.z); o.w = f2bf(v.w);
    ((ushort4*)(wsb + dst))[i] = o;
  }
}

// ---------------- 1) bf16 GEMM body, 2-phase double-buffered (T3 minimum recipe) ----------------
// C[m][n] = sum_k A[m][k]*B[n][k] + bias[n].  128 x (NF*32) tile, BK=32.
// Loop: { STAGE(next tile, buf^1); ds_read+MFMA on buf; vmcnt(0); barrier; flip }.
template<int NF>
__device__ __forceinline__ void gemm_body(
    const unsigned short* __restrict__ A, const unsigned short* __restrict__ Bw,
    const float* __restrict__ bias, void* __restrict__ Cv,
    int N, int bid, int out_bf16,
    unsigned short* As, unsigned short* Bs)
{
  const int K = 1024;
  const int BN = NF*32;
  const int nbn = N / BN;
  const int bm = bid / nbn, bn = bid % nbn;
  const int tid = threadIdx.x;
  const int l = tid & 63, w = tid >> 6;
  const int wm = w >> 1, wn = w & 1;
  const int li = l & 15, lg = l >> 4;
  const int ABUF = 128*32;
  const int BBUF = BN*32;

  f32x4 acc[4][NF];
  #pragma unroll
  for (int a = 0; a < 4; a++)
    #pragma unroll
    for (int b = 0; b < NF; b++) acc[a][b] = (f32x4){0.f,0.f,0.f,0.f};

  const size_t aBase = (size_t)(bm*128) * K;
  const size_t bBase = (size_t)(bn*BN) * K;

  // prologue: stage tile 0 into buf 0
  #pragma unroll
  for (int j = 0; j < 2; j++){
    int c = (w*2 + j)*64 + l;
    gload16(A + aBase + (size_t)(c >> 2)*K + (c & 3)*8, &As[(w*2+j)*512]);
  }
  #pragma unroll
  for (int j = 0; j < NF/2; j++){
    int c = (w*(NF/2) + j)*64 + l;
    gload16(Bw + bBase + (size_t)(c >> 2)*K + (c & 3)*8, &Bs[(w*(NF/2)+j)*512]);
  }
  asm volatile("s_waitcnt vmcnt(0)" ::: "memory");
  __syncthreads();

  int cur = 0;
  for (int kt = 0; kt < K; kt += 32){
    // issue next-tile staging first (overlaps with compute below)
    if (kt + 32 < K){
      int nb = cur ^ 1;
      #pragma unroll
      for (int j = 0; j < 2; j++){
        int c = (w*2 + j)*64 + l;
        gload16(A + aBase + (size_t)(c >> 2)*K + kt + 32 + (c & 3)*8,
                &As[nb*ABUF + (w*2+j)*512]);
      }
      #pragma unroll
      for (int j = 0; j < NF/2; j++){
        int c = (w*(NF/2) + j)*64 + l;
        gload16(Bw + bBase + (size_t)(c >> 2)*K + kt + 32 + (c & 3)*8,
                &Bs[nb*BBUF + (w*(NF/2)+j)*512]);
      }
    }
    // compute current buffer
    bf16x8 af[4], bfr[NF];
    const int ko = lg * 8;
    #pragma unroll
    for (int fm = 0; fm < 4; fm++)
      af[fm] = *(const bf16x8*)&As[cur*ABUF + (wm*64 + fm*16 + li)*32 + ko];
    #pragma unroll
    for (int fn = 0; fn < NF; fn++)
      bfr[fn] = *(const bf16x8*)&Bs[cur*BBUF + (wn*(NF*16) + fn*16 + li)*32 + ko];
    #pragma unroll
    for (int fm = 0; fm < 4; fm++)
      #pragma unroll
      for (int fn = 0; fn < NF; fn++)
        acc[fm][fn] = MFMA16(af[fm], bfr[fn], acc[fm][fn]);
    // publish staged tile
    asm volatile("s_waitcnt vmcnt(0)" ::: "memory");
    __syncthreads();
    cur ^= 1;
  }

  #pragma unroll
  for (int fm = 0; fm < 4; fm++){
    int m0 = bm*128 + wm*64 + fm*16 + lg*4;
    #pragma unroll
    for (int fn = 0; fn < NF; fn++){
      int n = bn*BN + wn*(NF*16) + fn*16 + li;
      float bv = bias[n];
      #pragma unroll
      for (int r = 0; r < 4; r++){
        float v = acc[fm][fn][r] + bv;
        if (out_bf16) ((unsigned short*)Cv)[(size_t)(m0+r)*N + n] = f2bf(v);
        else          ((float*)Cv)[(size_t)(m0+r)*N + n] = v;
      }
    }
  }
}

// word (384 tiles, N=3072) + speaker (256 tiles, N=2048) fused: 640 blocks
__global__ __launch_bounds__(256) void gemm_qkv(
    const unsigned short* __restrict__ XW, const unsigned short* __restrict__ WWORD,
    const unsigned short* __restrict__ XS, const unsigned short* __restrict__ WSPK,
    const float* __restrict__ FB,
    unsigned short* __restrict__ PWORD, unsigned short* __restrict__ PSPK)
{
  __shared__ unsigned short As[2*128*32];
  __shared__ unsigned short Bs[2*128*32];
  int bid = blockIdx.x;
  if (bid < 384)
    gemm_body<4>(XW, WWORD, FB,        PWORD, 3072, bid,       1, As, Bs);
  else
    gemm_body<4>(XS, WSPK,  FB + 3072, PSPK,  2048, bid - 384, 1, As, Bs);
}

// output projection: 128x64 tiles, 256 blocks
__global__ __launch_bounds__(256) void gemm_out(
    const unsigned short* __restrict__ CTX, const unsigned short* __restrict__ WOUT,
    const float* __restrict__ outb, float* __restrict__ outp)
{
  __shared__ unsigned short As[2*128*32];
  __shared__ unsigned short Bs[2*64*32];
  gemm_body<2>(CTX, WOUT, outb, outp, 1024, blockIdx.x, 0, As, Bs);
}

// ---------------- 2) rotary+LN (vectorized, table) + V transpose, one dispatch ----------------
__global__ __launch_bounds__(256) void postproc(
    unsigned short* __restrict__ Pw, unsigned short* __restrict__ Ps,
    const float* __restrict__ gamma, const float* __restrict__ beta,
    const float* __restrict__ TS, const float* __restrict__ TC,
    unsigned short* __restrict__ VT)
{
  __shared__ float lds[2320];
  int bx = blockIdx.x;
  int t = threadIdx.x;
  if (bx < 4096){
    int sec = bx & 3, rp = bx >> 2;
    int half = t >> 7, c = t & 127;
    int row = rp*2 + half;
    int seg = c >> 3, j = c & 7;
    unsigned short* p;
    if      (sec == 0) p = Pw + (size_t)row*3072 +        seg*64;
    else if (sec == 1) p = Pw + (size_t)row*3072 + 1024 + seg*64;
    else if (sec == 2) p = Ps + (size_t)row*2048 +        seg*64;
    else               p = Ps + (size_t)row*2048 + 1024 + seg*64;
    int pos = row & 1023;
    int sl  = half*16 + seg;

    ushort8_t xv = *(const ushort8_t*)(p + j*8);
    float4 sv = *(const float4*)&TS[pos*32 + j*4];
    float4 cv = *(const float4*)&TC[pos*32 + j*4];
    float ss[4] = {sv.x, sv.y, sv.z, sv.w};
    float cc[4] = {cv.x, cv.y, cv.z, cv.w};
    float y1[4], y2[4];
    #pragma unroll
    for (int k = 0; k < 4; k++){
      float x0 = bf2f(xv[2*k]), x1 = bf2f(xv[2*k+1]);
      y1[k] = x0*cc[k] - x1*ss[k];
      y2[k] = x0*ss[k] + x1*cc[k];
    }
    *(float4*)&lds[sl*68 + j*4]      = (float4){y1[0], y1[1], y1[2], y1[3]};
    *(float4*)&lds[sl*68 + 32 + j*4] = (float4){y2[0], y2[1], y2[2], y2[3]};
    __syncthreads();

    float4 a0 = *(const float4*)&lds[sl*68 + j*8];
    float4 a1 = *(const float4*)&lds[sl*68 + j*8 + 4];
    float v[8] = {a0.x, a0.y, a0.z, a0.w, a1.x, a1.y, a1.z, a1.w};
    float s = 0.f;
    #pragma unroll
    for (int k = 0; k < 8; k++) s += v[k];
    #pragma unroll
    for (int o = 1; o < 8; o <<= 1) s += __shfl_xor(s, o);
    float mu = s * (1.f/64.f);
    float sq = 0.f;
    #pragma unroll
    for (int k = 0; k < 8; k++){ float d = v[k] - mu; sq += d*d; }
    #pragma unroll
    for (int o = 1; o < 8; o <<= 1) sq += __shfl_xor(sq, o);
    float rs = rsqrtf(sq * (1.f/64.f) + 1e-5f);
    float4 g0 = *(const float4*)&gamma[j*8], g1 = *(const float4*)&gamma[j*8+4];
    float4 b0 = *(const float4*)&beta[j*8],  b1 = *(const float4*)&beta[j*8+4];
    float gg[8] = {g0.x,g0.y,g0.z,g0.w,g1.x,g1.y,g1.z,g1.w};
    float bb[8] = {b0.x,b0.y,b0.z,b0.w,b1.x,b1.y,b1.z,b1.w};
    ushort8_t o8;
    #pragma unroll
    for (int k = 0; k < 8; k++) o8[k] = f2bf((v[k]-mu)*rs*gg[k] + bb[k]);
    *(ushort8_t*)(p + j*8) = o8;
  } else {
    unsigned short* tp = (unsigned short*)lds;   // 64 x 72
    int bid2 = bx - 4096;
    int bh = bid2 >> 4, lt = bid2 & 15;
    int b = bh >> 4, h = bh & 15;
    #pragma unroll
    for (int i = 0; i < 2; i++){
      int cc2 = t + i*256;
      int row = cc2 >> 3, co = (cc2 & 7)*8;
      const unsigned short* src = Pw + (size_t)(b*1024 + lt*64 + row)*3072 + 2048 + h*64 + co;
      *(uint4*)&tp[row*72 + co] = *(const uint4*)src;
    }
    __syncthreads();
    int d = t >> 2, jb = (t & 3)*16;
    unsigned short o[16];
    #pragma unroll
    for (int j = 0; j < 16; j++) o[j] = tp[(jb + j)*72 + d];
    unsigned short* dst = VT + ((size_t)bh*64 + d)*1024 + lt*64 + jb;
    *(uint4*)dst       = *(uint4*)&o[0];
    *(uint4*)(dst + 8) = *(uint4*)&o[8];
  }
}

// ---------------- 3) fused attention, LDS-staged, fixed-max softmax ----------------
// grid 256 = (b, h, qq); 8 waves. Waves 0-3: q-band qt=qq, waves 4-7: qt=15-qq.
__global__ __launch_bounds__(512) void attn_fused(
    const unsigned short* __restrict__ Pw, const unsigned short* __restrict__ Ps,
    const unsigned short* __restrict__ VTg,
    float* __restrict__ attn, unsigned short* __restrict__ Ctx)
{
  // LDS: KW[2][64][72] | KS[2][64][72] | VT[2][64][72] | PT[8][16][72]
  __shared__ unsigned short SL[36864];   // 73728 B

  int bx = blockIdx.x;
  int b = bx >> 7, rem = bx & 127, h = rem >> 3, qq = rem & 7;
  int maxkt = 15 - qq;
  int tid = threadIdx.x;
  int w = tid >> 6, l = tid & 63;
  int g = w >> 2, wsub = w & 3;
  int qt = g ? maxkt : qq;
  int lg = l >> 4, li = l & 15;
  int q0 = qt*64 + wsub*16;
  int bh = b*16 + h;

  int srow = tid >> 3, scb = tid & 7;      // staging: row 0..63, 16B chunk 0..7
  const unsigned short* gKW = Pw + (size_t)(b*1024)*3072 + 1024 + h*64;
  const unsigned short* gKS = Ps + (size_t)(b*1024)*2048 + 1024 + h*64;
  const unsigned short* gVT = VTg + (size_t)bh*64*1024;
  unsigned short* pt = SL + 27648 + w*1152;

  // Q fragments
  bf16x8 aqw[2], aqs[2];
  {
    int q = q0 + li;
    const unsigned short* pqw = Pw + (size_t)(b*1024 + q)*3072 + h*64 + lg*8;
    const unsigned short* pqs = Ps + (size_t)(b*1024 + q)*2048 + h*64 + lg*8;
    aqw[0] = *(const bf16x8*)pqw;  aqw[1] = *(const bf16x8*)(pqw + 32);
    aqs[0] = *(const bf16x8*)pqs;  aqs[1] = *(const bf16x8*)(pqs + 32);
  }
  const float rscale = 0.08838834764831845f;   // 1/sqrt(2*HD)

  uint4 rkw, rks, rvt;

  // ---- sweep 1: row sums ----
  float ps4[4] = {0.f, 0.f, 0.f, 0.f};
  rkw = *(const uint4*)(gKW + (size_t)srow*3072 + scb*8);
  rks = *(const uint4*)(gKS + (size_t)srow*2048 + scb*8);
  *(uint4*)(SL +        srow*72 + scb*8) = rkw;
  *(uint4*)(SL + 9216 + srow*72 + scb*8) = rks;

  for (int kt = 0; kt <= maxkt; ++kt){
    int buf = kt & 1;
    if (kt < maxkt){
      rkw = *(const uint4*)(gKW + (size_t)((kt+1)*64 + srow)*3072 + scb*8);
      rks = *(const uint4*)(gKS + (size_t)((kt+1)*64 + srow)*2048 + scb*8);
    }
    __syncthreads();
    if (kt <= qt){
      const unsigned short* KWt = SL +        buf*4608;
      const unsigned short* KSt = SL + 9216 + buf*4608;
      f32x4 s[4];
      #pragma unroll
      for (int fn = 0; fn < 4; fn++){
        s[fn] = (f32x4){0.f,0.f,0.f,0.f};
        int rr = (fn*16 + li)*72;
        bf16x8 k0 = *(const bf16x8*)(KWt + rr + lg*8);
        bf16x8 k1 = *(const bf16x8*)(KWt + rr + 32 + lg*8);
        bf16x8 k2 = *(const bf16x8*)(KSt + rr + lg*8);
        bf16x8 k3 = *(const bf16x8*)(KSt + rr + 32 + lg*8);
        s[fn] = MFMA16(aqw[0], k0, s[fn]);
        s[fn] = MFMA16(aqw[1], k1, s[fn]);
        s[fn] = MFMA16(aqs[0], k2, s[fn]);
        s[fn] = MFMA16(aqs[1], k3, s[fn]);
      }
      #pragma unroll
      for (int r = 0; r < 4; r++){
        int q = q0 + lg*4 + r;
        #pragma unroll
        for (int fn = 0; fn < 4; fn++){
          int k = kt*64 + fn*16 + li;
          float e = __expf(s[fn][r] * rscale);
          ps4[r] += (k <= q) ? e : 0.f;
        }
      }
    }
    if (kt < maxkt){
      int nb = buf ^ 1;
      *(uint4*)(SL +        nb*4608 + srow*72 + scb*8) = rkw;
      *(uint4*)(SL + 9216 + nb*4608 + srow*72 + scb*8) = rks;
    }
  }
  #pragma unroll
  for (int r = 0; r < 4; r++){
    #pragma unroll
    for (int o = 1; o < 16; o <<= 1) ps4[r] += __shfl_xor(ps4[r], o);
  }
  float rinv[4];
  #pragma unroll
  for (int r = 0; r < 4; r++) rinv[r] = 1.f / ps4[r];

  // ---- sweep 2: recompute, normalize, write attn, PV ----
  __syncthreads();   // sweep1 reads done before re-staging buf0
  rkw = *(const uint4*)(gKW + (size_t)srow*3072 + scb*8);
  rks = *(const uint4*)(gKS + (size_t)srow*2048 + scb*8);
  rvt = *(const uint4*)(gVT + (size_t)srow*1024 + scb*8);
  *(uint4*)(SL +         srow*72 + scb*8) = rkw;
  *(uint4*)(SL +  9216 + srow*72 + scb*8) = rks;
  *(uint4*)(SL + 18432 + srow*72 + scb*8) = rvt;

  f32x4 c[4];
  #pragma unroll
  for (int fn = 0; fn < 4; fn++) c[fn] = (f32x4){0.f,0.f,0.f,0.f};

  for (int kt = 0; kt < 16; ++kt){
    int buf = kt & 1;
    if (kt < maxkt){
      rkw = *(const uint4*)(gKW + (size_t)((kt+1)*64 + srow)*3072 + scb*8);
      rks = *(const uint4*)(gKS + (size_t)((kt+1)*64 + srow)*2048 + scb*8);
      rvt = *(const uint4*)(gVT + (size_t)srow*1024 + (kt+1)*64 + scb*8);
    }
    __syncthreads();
    float* abase = attn + ((size_t)bh*1024 + q0 + li)*1024 + kt*64;
    if (kt <= qt){
      const unsigned short* KWt = SL +         buf*4608;
      const unsigned short* KSt = SL +  9216 + buf*4608;
      const unsigned short* VTt = SL + 18432 + buf*4608;
      f32x4 s[4];
      #pragma unroll
      for (int fn = 0; fn < 4; fn++){
        s[fn] = (f32x4){0.f,0.f,0.f,0.f};
        int rr = (fn*16 + li)*72;
        bf16x8 k0 = *(const bf16x8*)(KWt + rr + lg*8);
        bf16x8 k1 = *(const bf16x8*)(KWt + rr + 32 + lg*8);
        bf16x8 k2 = *(const bf16x8*)(KSt + rr + lg*8);
        bf16x8 k3 = *(const bf16x8*)(KSt + rr + 32 + lg*8);
        s[fn] = MFMA16(aqw[0], k0, s[fn]);
        s[fn] = MFMA16(aqw[1], k1, s[fn]);
        s[fn] = MFMA16(aqs[0], k2, s[fn]);
        s[fn] = MFMA16(aqs[1], k3, s[fn]);
      }
      #pragma unroll
      for (int fn = 0; fn < 4; fn++){
        #pragma unroll
        for (int r = 0; r < 4; r++){
          int k = kt*64 + fn*16 + li;
          int q = q0 + lg*4 + r;
          float pp = (k <= q) ? __expf(s[fn][r] * rscale) * rinv[r] : 0.f;
          pt[(lg*4 + r)*72 + fn*16 + li] = f2bf(pp);
        }
      }
      asm volatile("s_waitcnt lgkmcnt(0)" ::: "memory");
      __builtin_amdgcn_sched_barrier(0);
      bf16x8 af0 = *(const bf16x8*)(pt + li*72 + lg*8);
      bf16x8 af1 = *(const bf16x8*)(pt + li*72 + 32 + lg*8);
      ushort8_t u0 = __builtin_bit_cast(ushort8_t, af0);
      ushort8_t u1 = __builtin_bit_cast(ushort8_t, af1);
      *(float4*)(abase + lg*8)          = (float4){bf2f(u0[0]),bf2f(u0[1]),bf2f(u0[2]),bf2f(u0[3])};
      *(float4*)(abase + lg*8 + 4)      = (float4){bf2f(u0[4]),bf2f(u0[5]),bf2f(u0[6]),bf2f(u0[7])};
      *(float4*)(abase + 32 + lg*8)     = (float4){bf2f(u1[0]),bf2f(u1[1]),bf2f(u1[2]),bf2f(u1[3])};
      *(float4*)(abase + 32 + lg*8 + 4) = (float4){bf2f(u1[4]),bf2f(u1[5]),bf2f(u1[6]),bf2f(u1[7])};
      #pragma unroll
      for (int fn = 0; fn < 4; fn++){
        int rr = (fn*16 + li)*72;
        bf16x8 v0 = *(const bf16x8*)(VTt + rr + lg*8);
        bf16x8 v1 = *(const bf16x8*)(VTt + rr + 32 + lg*8);
        c[fn] = MFMA16(af0, v0, c[fn]);
        c[fn] = MFMA16(af1, v1, c[fn]);
      }
    } else {
      float4 z = {0.f, 0.f, 0.f, 0.f};
      *(float4*)(abase + lg*8)          = z;
      *(float4*)(abase + lg*8 + 4)      = z;
      *(float4*)(abase + 32 + lg*8)     = z;
      *(float4*)(abase + 32 + lg*8 + 4) = z;
    }
    if (kt < maxkt){
      int nb = buf ^ 1;
      *(uint4*)(SL +         nb*4608 + srow*72 + scb*8) = rkw;
      *(uint4*)(SL +  9216 + nb*4608 + srow*72 + scb*8) = rks;
      *(uint4*)(SL + 18432 + nb*4608 + srow*72 + scb*8) = rvt;
    }
  }

  // ctx write: D layout row=(l>>4)*4+r, col=l&15  (re-read by gemm_out -> keep cached)
  #pragma unroll
  for (int fn = 0; fn < 4; fn++){
    #pragma unroll
    for (int r = 0; r < 4; r++){
      int q = q0 + lg*4 + r;
      int d = fn*16 + li;
      Ctx[(size_t)(b*1024 + q)*1024 + h*64 + d] = f2bf(c[fn][r]);
    }
  }
}

// ---------------- host launch ----------------
extern "C" void kernel_launch(void* const* d_in, const int* in_sizes, int n_in,
                              void* d_out, int out_size, void* d_ws, size_t ws_size,
                              hipStream_t stream)
{
  (void)in_sizes; (void)n_in; (void)out_size; (void)ws_size;
  const float* word = (const float*)d_in[0];
  const float* spk  = (const float*)d_in[1];
  const float* qww  = (const float*)d_in[3];
  const float* qwb  = (const float*)d_in[4];
  const float* kww  = (const float*)d_in[5];
  const float* kwb  = (const float*)d_in[6];
  const float* qsw  = (const float*)d_in[7];
  const float* qsb  = (const float*)d_in[8];
  const float* ksw  = (const float*)d_in[9];
  const float* ksb  = (const float*)d_in[10];
  const float* vw   = (const float*)d_in[11];
  const float* vb   = (const float*)d_in[12];
  const float* outw = (const float*)d_in[13];
  const float* outb = (const float*)d_in[14];
  const float* gamma= (const float*)d_in[15];
  const float* beta = (const float*)d_in[16];

  unsigned short* U = (unsigned short*)d_ws;
  unsigned short* XW    = U + E_XW;
  unsigned short* XS    = U + E_XS;
  unsigned short* WWORD = U + E_WWORD;
  unsigned short* WSPK  = U + E_WSPK;
  unsigned short* WOUT  = U + E_WOUT;
  unsigned short* PWORD = U + E_PWORD;
  unsigned short* PSPK  = U + E_PSPK;
  unsigned short* VT    = U + E_VT;
  unsigned short* CTX   = U + E_CTX;
  float* FB = (float*)(U + E_END);
  float* TS = FB + 5120;
  float* TC = TS + 32768;

  float* outp = (float*)d_out;
  float* attn = outp + (size_t)2*1024*1024;

  convert_all<<<4096, 256, 0, stream>>>(word, spk, qww, kww, vw, qsw, ksw, outw,
                                        qwb, kwb, vb, qsb, ksb, U, FB);
  gemm_qkv<<<640, 256, 0, stream>>>(XW, WWORD, XS, WSPK, FB, PWORD, PSPK);
  postproc<<<4608, 256, 0, stream>>>(PWORD, PSPK, gamma, beta, TS, TC, VT);
  attn_fused<<<256, 512, 0, stream>>>(PWORD, PSPK, VT, attn, CTX);
  gemm_out<<<256, 256, 0, stream>>>(CTX, WOUT, outb, outp);
}

// Round 9
// 117.843 us; speedup vs baseline: 1.6137x; 1.1706x over previous
//
#include <hip/hip_runtime.h>
#include <cstdint>
#include <cstddef>

// ---------------- types & helpers ----------------
typedef __bf16 bf16x8 __attribute__((ext_vector_type(8)));
typedef float  f32x4  __attribute__((ext_vector_type(4)));
typedef unsigned short ushort8_t __attribute__((ext_vector_type(8)));

__device__ __forceinline__ unsigned short f2bf(float f){
  unsigned u = __builtin_bit_cast(unsigned, f);
  u += 0x7fffu + ((u >> 16) & 1u);
  return (unsigned short)(u >> 16);
}
__device__ __forceinline__ float bf2f(unsigned short s){
  return __builtin_bit_cast(float, ((unsigned)s) << 16);
}

#define MFMA16(a,b,c) __builtin_amdgcn_mfma_f32_16x16x32_bf16((a),(b),(c),0,0,0)

__device__ __forceinline__ void gload16(const void* g, void* lds){
  __builtin_amdgcn_global_load_lds(
      (const __attribute__((address_space(1))) void*)g,
      (__attribute__((address_space(3))) void*)lds, 16, 0, 0);
}

// ---------------- workspace layout (ushort element offsets) ----------------
#define E_XW    ((size_t)0)                          // word bf16 (2048x1024)
#define E_XS    (E_XW    + (size_t)2048*1024)        // speaker bf16
#define E_WWORD (E_XS    + (size_t)2048*1024)        // [qw_w; kw_w; v_w] (3072x1024)
#define E_WSPK  (E_WWORD + (size_t)3072*1024)        // [qs_w; ks_w] (2048x1024)
#define E_WOUT  (E_WSPK  + (size_t)2048*1024)        // out_w (1024x1024)
#define E_PWORD (E_WOUT  + (size_t)1024*1024)        // proj word (2048x3072): qw|kw|v
#define E_PSPK  (E_PWORD + (size_t)2048*3072)        // proj spk  (2048x2048): qs|ks
#define E_VT    (E_PSPK  + (size_t)2048*2048)        // V^T (32 heads x 64 x 1024)
#define E_CTX   (E_VT    + (size_t)2048*1024)        // ctx bf16 (2048x1024)
#define E_END   (E_CTX   + (size_t)2048*1024)

// ---------------- 0) fp32 -> bf16 conversion + rope tables + bias concat ----------------
__global__ __launch_bounds__(256) void convert_all(
    const float* __restrict__ word, const float* __restrict__ spk,
    const float* __restrict__ qww,  const float* __restrict__ kww,
    const float* __restrict__ vw,   const float* __restrict__ qsw,
    const float* __restrict__ ksw,  const float* __restrict__ outw,
    const float* __restrict__ qwb,  const float* __restrict__ kwb,
    const float* __restrict__ vb,   const float* __restrict__ qsb,
    const float* __restrict__ ksb,
    unsigned short* __restrict__ wsb, float* __restrict__ FB)
{
  int idx = blockIdx.x*256 + threadIdx.x;
  if (idx < 32768){
    int pos = idx >> 5, i = idx & 31;
    float inv = expf((float)(2*i) * -0.14391157f);   // exp(2i * -ln(1e4)/64)
    float ang = (float)pos * inv;
    float sv, cv; sincosf(ang, &sv, &cv);
    FB[5120 + idx]         = sv;   // TS
    FB[5120 + 32768 + idx] = cv;   // TC
  } else if (idx < 33792){
    int i = idx - 32768;
    FB[i] = qwb[i]; FB[1024+i] = kwb[i]; FB[2048+i] = vb[i];
    FB[3072+i] = qsb[i]; FB[3072+1024+i] = ksb[i];
  }

  const size_t total = 2621440;  // float4 chunks
  for (size_t c = (size_t)blockIdx.x*256 + threadIdx.x; c < total;
       c += (size_t)gridDim.x*256){
    const float* src; size_t dst; size_t i;
    if (c < 524288)       { src = word; dst = E_XW; i = c; }
    else if (c < 1048576) { src = spk;  dst = E_XS; i = c - 524288; }
    else {
      size_t t = c - 1048576; int seg = (int)(t >> 18); i = t & 262143;
      switch (seg){
        case 0:  src = qww; dst = E_WWORD;                      break;
        case 1:  src = kww; dst = E_WWORD + (size_t)1048576;    break;
        case 2:  src = vw;  dst = E_WWORD + (size_t)2097152;    break;
        case 3:  src = qsw; dst = E_WSPK;                       break;
        case 4:  src = ksw; dst = E_WSPK  + (size_t)1048576;    break;
        default: src = outw; dst = E_WOUT;                      break;
      }
    }
    float4 v = ((const float4*)src)[i];
    ushort4 o; o.x = f2bf(v.x); o.y = f2bf(v.y); o.z = f2bf(v.z); o.w = f2bf(v.w);
    ((ushort4*)(wsb + dst))[i] = o;
  }
}

// ---------------- 1) bf16 GEMM body (round-3 single-buffered m97 structure) ----------------
// C[m][n] = sum_k A[m][k]*B[n][k] + bias[n].  128 x (NF*32) tile, BK=32.
template<int NF>
__device__ __forceinline__ void gemm_body(
    const unsigned short* __restrict__ A, const unsigned short* __restrict__ Bw,
    const float* __restrict__ bias, void* __restrict__ Cv,
    int N, int bid, int out_bf16,
    unsigned short* As, unsigned short* Bs)
{
  const int K = 1024;
  const int BN = NF*32;
  const int nbn = N / BN;
  const int bm = bid / nbn, bn = bid % nbn;
  const int tid = threadIdx.x;
  const int l = tid & 63, w = tid >> 6;
  const int wm = w >> 1, wn = w & 1;
  const int li = l & 15, lg = l >> 4;

  f32x4 acc[4][NF];
  #pragma unroll
  for (int a = 0; a < 4; a++)
    #pragma unroll
    for (int b = 0; b < NF; b++) acc[a][b] = (f32x4){0.f,0.f,0.f,0.f};

  const int colS = (l & 3) * 8;
  const size_t aBase = (size_t)(bm*128) * K;
  const size_t bBase = (size_t)(bn*BN) * K;

  for (int kt = 0; kt < K; kt += 32){
    #pragma unroll
    for (int j = 0; j < 2; j++){
      int row = (w*2 + j)*16 + (l >> 2);
      gload16(A + aBase + (size_t)row*K + kt + colS, &As[(size_t)(w*2+j)*512]);
    }
    if (NF == 4){
      #pragma unroll
      for (int j = 0; j < 2; j++){
        int row = (w*2 + j)*16 + (l >> 2);
        gload16(Bw + bBase + (size_t)row*K + kt + colS, &Bs[(size_t)(w*2+j)*512]);
      }
    } else {
      int row = w*16 + (l >> 2);
      gload16(Bw + bBase + (size_t)row*K + kt + colS, &Bs[(size_t)w*512]);
    }
    asm volatile("s_waitcnt vmcnt(0)" ::: "memory");
    __syncthreads();

    bf16x8 af[4], bfr[NF];
    const int ko = lg * 8;
    #pragma unroll
    for (int fm = 0; fm < 4; fm++)
      af[fm] = *(const bf16x8*)&As[(wm*64 + fm*16 + li)*32 + ko];
    #pragma unroll
    for (int fn = 0; fn < NF; fn++)
      bfr[fn] = *(const bf16x8*)&Bs[(wn*(NF*16) + fn*16 + li)*32 + ko];
    #pragma unroll
    for (int fm = 0; fm < 4; fm++)
      #pragma unroll
      for (int fn = 0; fn < NF; fn++)
        acc[fm][fn] = MFMA16(af[fm], bfr[fn], acc[fm][fn]);
    __syncthreads();
  }

  #pragma unroll
  for (int fm = 0; fm < 4; fm++){
    int m0 = bm*128 + wm*64 + fm*16 + lg*4;
    #pragma unroll
    for (int fn = 0; fn < NF; fn++){
      int n = bn*BN + wn*(NF*16) + fn*16 + li;
      float bv = bias[n];
      #pragma unroll
      for (int r = 0; r < 4; r++){
        float v = acc[fm][fn][r] + bv;
        if (out_bf16) ((unsigned short*)Cv)[(size_t)(m0+r)*N + n] = f2bf(v);
        else          ((float*)Cv)[(size_t)(m0+r)*N + n] = v;
      }
    }
  }
}

// word (384 tiles, N=3072) + speaker (256 tiles, N=2048): 640 blocks, XCD-swizzled
__global__ __launch_bounds__(256) void gemm_qkv(
    const unsigned short* __restrict__ XW, const unsigned short* __restrict__ WWORD,
    const unsigned short* __restrict__ XS, const unsigned short* __restrict__ WSPK,
    const float* __restrict__ FB,
    unsigned short* __restrict__ PWORD, unsigned short* __restrict__ PSPK)
{
  __shared__ unsigned short As[128*32];
  __shared__ unsigned short Bs[128*32];
  int raw = blockIdx.x;
  int bid = (raw & 7)*80 + (raw >> 3);   // 640 blocks: bijective XCD swizzle (T1)
  if (bid < 384)
    gemm_body<4>(XW, WWORD, FB,        PWORD, 3072, bid,       1, As, Bs);
  else
    gemm_body<4>(XS, WSPK,  FB + 3072, PSPK,  2048, bid - 384, 1, As, Bs);
}

// output projection: 128x64 tiles, 256 blocks, XCD-swizzled
__global__ __launch_bounds__(256) void gemm_out(
    const unsigned short* __restrict__ CTX, const unsigned short* __restrict__ WOUT,
    const float* __restrict__ outb, float* __restrict__ outp)
{
  __shared__ unsigned short As[128*32];
  __shared__ unsigned short Bs[64*32];
  int raw = blockIdx.x;
  int bid = (raw & 7)*32 + (raw >> 3);   // 256 blocks
  gemm_body<2>(CTX, WOUT, outb, outp, 1024, bid, 0, As, Bs);
}

// ---------------- 2) rotary+LN (vectorized, table) + V transpose, one dispatch ----------------
__global__ __launch_bounds__(256) void postproc(
    unsigned short* __restrict__ Pw, unsigned short* __restrict__ Ps,
    const float* __restrict__ gamma, const float* __restrict__ beta,
    const float* __restrict__ TS, const float* __restrict__ TC,
    unsigned short* __restrict__ VT)
{
  __shared__ float lds[2320];
  int bx = blockIdx.x;
  int t = threadIdx.x;
  if (bx < 4096){
    int sec = bx & 3, rp = bx >> 2;
    int half = t >> 7, c = t & 127;
    int row = rp*2 + half;
    int seg = c >> 3, j = c & 7;
    unsigned short* p;
    if      (sec == 0) p = Pw + (size_t)row*3072 +        seg*64;
    else if (sec == 1) p = Pw + (size_t)row*3072 + 1024 + seg*64;
    else if (sec == 2) p = Ps + (size_t)row*2048 +        seg*64;
    else               p = Ps + (size_t)row*2048 + 1024 + seg*64;
    int pos = row & 1023;
    int sl  = half*16 + seg;

    ushort8_t xv = *(const ushort8_t*)(p + j*8);
    float4 sv = *(const float4*)&TS[pos*32 + j*4];
    float4 cv = *(const float4*)&TC[pos*32 + j*4];
    float ss[4] = {sv.x, sv.y, sv.z, sv.w};
    float cc[4] = {cv.x, cv.y, cv.z, cv.w};
    float y1[4], y2[4];
    #pragma unroll
    for (int k = 0; k < 4; k++){
      float x0 = bf2f(xv[2*k]), x1 = bf2f(xv[2*k+1]);
      y1[k] = x0*cc[k] - x1*ss[k];
      y2[k] = x0*ss[k] + x1*cc[k];
    }
    *(float4*)&lds[sl*68 + j*4]      = (float4){y1[0], y1[1], y1[2], y1[3]};
    *(float4*)&lds[sl*68 + 32 + j*4] = (float4){y2[0], y2[1], y2[2], y2[3]};
    __syncthreads();

    float4 a0 = *(const float4*)&lds[sl*68 + j*8];
    float4 a1 = *(const float4*)&lds[sl*68 + j*8 + 4];
    float v[8] = {a0.x, a0.y, a0.z, a0.w, a1.x, a1.y, a1.z, a1.w};
    float s = 0.f;
    #pragma unroll
    for (int k = 0; k < 8; k++) s += v[k];
    #pragma unroll
    for (int o = 1; o < 8; o <<= 1) s += __shfl_xor(s, o);
    float mu = s * (1.f/64.f);
    float sq = 0.f;
    #pragma unroll
    for (int k = 0; k < 8; k++){ float d = v[k] - mu; sq += d*d; }
    #pragma unroll
    for (int o = 1; o < 8; o <<= 1) sq += __shfl_xor(sq, o);
    float rs = rsqrtf(sq * (1.f/64.f) + 1e-5f);
    float4 g0 = *(const float4*)&gamma[j*8], g1 = *(const float4*)&gamma[j*8+4];
    float4 b0 = *(const float4*)&beta[j*8],  b1 = *(const float4*)&beta[j*8+4];
    float gg[8] = {g0.x,g0.y,g0.z,g0.w,g1.x,g1.y,g1.z,g1.w};
    float bb[8] = {b0.x,b0.y,b0.z,b0.w,b1.x,b1.y,b1.z,b1.w};
    ushort8_t o8;
    #pragma unroll
    for (int k = 0; k < 8; k++) o8[k] = f2bf((v[k]-mu)*rs*gg[k] + bb[k]);
    *(ushort8_t*)(p + j*8) = o8;
  } else {
    unsigned short* tp = (unsigned short*)lds;   // 64 x 72
    int bid2 = bx - 4096;
    int bh = bid2 >> 4, lt = bid2 & 15;
    int b = bh >> 4, h = bh & 15;
    #pragma unroll
    for (int i = 0; i < 2; i++){
      int cc2 = t + i*256;
      int row = cc2 >> 3, co = (cc2 & 7)*8;
      const unsigned short* src = Pw + (size_t)(b*1024 + lt*64 + row)*3072 + 2048 + h*64 + co;
      *(uint4*)&tp[row*72 + co] = *(const uint4*)src;
    }
    __syncthreads();
    int d = t >> 2, jb = (t & 3)*16;
    unsigned short o[16];
    #pragma unroll
    for (int j = 0; j < 16; j++) o[j] = tp[(jb + j)*72 + d];
    unsigned short* dst = VT + ((size_t)bh*64 + d)*1024 + lt*64 + jb;
    *(uint4*)dst       = *(uint4*)&o[0];
    *(uint4*)(dst + 8) = *(uint4*)&o[8];
  }
}

// ---------------- 3) fused attention, LDS-staged, fixed-max softmax ----------------
// grid 256 = (b, h, qq); 8 waves. Waves 0-3: q-band qt=qq, waves 4-7: qt=15-qq.
__global__ __launch_bounds__(512) void attn_fused(
    const unsigned short* __restrict__ Pw, const unsigned short* __restrict__ Ps,
    const unsigned short* __restrict__ VTg,
    float* __restrict__ attn, unsigned short* __restrict__ Ctx)
{
  // LDS: KW[2][64][72] | KS[2][64][72] | VT[2][64][72] | PT[8][16][72]
  __shared__ unsigned short SL[36864];   // 73728 B

  int bx = blockIdx.x;
  int b = bx >> 7, rem = bx & 127, h = rem >> 3, qq = rem & 7;
  int maxkt = 15 - qq;
  int tid = threadIdx.x;
  int w = tid >> 6, l = tid & 63;
  int g = w >> 2, wsub = w & 3;
  int qt = g ? maxkt : qq;
  int lg = l >> 4, li = l & 15;
  int q0 = qt*64 + wsub*16;
  int bh = b*16 + h;

  int srow = tid >> 3, scb = tid & 7;      // staging: row 0..63, 16B chunk 0..7
  const unsigned short* gKW = Pw + (size_t)(b*1024)*3072 + 1024 + h*64;
  const unsigned short* gKS = Ps + (size_t)(b*1024)*2048 + 1024 + h*64;
  const unsigned short* gVT = VTg + (size_t)bh*64*1024;
  unsigned short* pt = SL + 27648 + w*1152;

  // Q fragments
  bf16x8 aqw[2], aqs[2];
  {
    int q = q0 + li;
    const unsigned short* pqw = Pw + (size_t)(b*1024 + q)*3072 + h*64 + lg*8;
    const unsigned short* pqs = Ps + (size_t)(b*1024 + q)*2048 + h*64 + lg*8;
    aqw[0] = *(const bf16x8*)pqw;  aqw[1] = *(const bf16x8*)(pqw + 32);
    aqs[0] = *(const bf16x8*)pqs;  aqs[1] = *(const bf16x8*)(pqs + 32);
  }
  const float rscale = 0.08838834764831845f;   // 1/sqrt(2*HD)

  uint4 rkw, rks, rvt;

  // ---- sweep 1: row sums ----
  float ps4[4] = {0.f, 0.f, 0.f, 0.f};
  rkw = *(const uint4*)(gKW + (size_t)srow*3072 + scb*8);
  rks = *(const uint4*)(gKS + (size_t)srow*2048 + scb*8);
  *(uint4*)(SL +        srow*72 + scb*8) = rkw;
  *(uint4*)(SL + 9216 + srow*72 + scb*8) = rks;

  for (int kt = 0; kt <= maxkt; ++kt){
    int buf = kt & 1;
    if (kt < maxkt){
      rkw = *(const uint4*)(gKW + (size_t)((kt+1)*64 + srow)*3072 + scb*8);
      rks = *(const uint4*)(gKS + (size_t)((kt+1)*64 + srow)*2048 + scb*8);
    }
    __syncthreads();
    if (kt <= qt){
      const unsigned short* KWt = SL +        buf*4608;
      const unsigned short* KSt = SL + 9216 + buf*4608;
      f32x4 s[4];
      #pragma unroll
      for (int fn = 0; fn < 4; fn++){
        s[fn] = (f32x4){0.f,0.f,0.f,0.f};
        int rr = (fn*16 + li)*72;
        bf16x8 k0 = *(const bf16x8*)(KWt + rr + lg*8);
        bf16x8 k1 = *(const bf16x8*)(KWt + rr + 32 + lg*8);
        bf16x8 k2 = *(const bf16x8*)(KSt + rr + lg*8);
        bf16x8 k3 = *(const bf16x8*)(KSt + rr + 32 + lg*8);
        s[fn] = MFMA16(aqw[0], k0, s[fn]);
        s[fn] = MFMA16(aqw[1], k1, s[fn]);
        s[fn] = MFMA16(aqs[0], k2, s[fn]);
        s[fn] = MFMA16(aqs[1], k3, s[fn]);
      }
      #pragma unroll
      for (int r = 0; r < 4; r++){
        int q = q0 + lg*4 + r;
        #pragma unroll
        for (int fn = 0; fn < 4; fn++){
          int k = kt*64 + fn*16 + li;
          float e = __expf(s[fn][r] * rscale);
          ps4[r] += (k <= q) ? e : 0.f;
        }
      }
    }
    if (kt < maxkt){
      int nb = buf ^ 1;
      *(uint4*)(SL +        nb*4608 + srow*72 + scb*8) = rkw;
      *(uint4*)(SL + 9216 + nb*4608 + srow*72 + scb*8) = rks;
    }
  }
  #pragma unroll
  for (int r = 0; r < 4; r++){
    #pragma unroll
    for (int o = 1; o < 16; o <<= 1) ps4[r] += __shfl_xor(ps4[r], o);
  }
  float rinv[4];
  #pragma unroll
  for (int r = 0; r < 4; r++) rinv[r] = 1.f / ps4[r];

  // ---- sweep 2: recompute, normalize, write attn, PV ----
  __syncthreads();   // sweep1 reads done before re-staging buf0
  rkw = *(const uint4*)(gKW + (size_t)srow*3072 + scb*8);
  rks = *(const uint4*)(gKS + (size_t)srow*2048 + scb*8);
  rvt = *(const uint4*)(gVT + (size_t)srow*1024 + scb*8);
  *(uint4*)(SL +         srow*72 + scb*8) = rkw;
  *(uint4*)(SL +  9216 + srow*72 + scb*8) = rks;
  *(uint4*)(SL + 18432 + srow*72 + scb*8) = rvt;

  f32x4 c[4];
  #pragma unroll
  for (int fn = 0; fn < 4; fn++) c[fn] = (f32x4){0.f,0.f,0.f,0.f};

  for (int kt = 0; kt < 16; ++kt){
    int buf = kt & 1;
    if (kt < maxkt){
      rkw = *(const uint4*)(gKW + (size_t)((kt+1)*64 + srow)*3072 + scb*8);
      rks = *(const uint4*)(gKS + (size_t)((kt+1)*64 + srow)*2048 + scb*8);
      rvt = *(const uint4*)(gVT + (size_t)srow*1024 + (kt+1)*64 + scb*8);
    }
    __syncthreads();
    float* abase = attn + ((size_t)bh*1024 + q0 + li)*1024 + kt*64;
    if (kt <= qt){
      const unsigned short* KWt = SL +         buf*4608;
      const unsigned short* KSt = SL +  9216 + buf*4608;
      const unsigned short* VTt = SL + 18432 + buf*4608;
      f32x4 s[4];
      #pragma unroll
      for (int fn = 0; fn < 4; fn++){
        s[fn] = (f32x4){0.f,0.f,0.f,0.f};
        int rr = (fn*16 + li)*72;
        bf16x8 k0 = *(const bf16x8*)(KWt + rr + lg*8);
        bf16x8 k1 = *(const bf16x8*)(KWt + rr + 32 + lg*8);
        bf16x8 k2 = *(const bf16x8*)(KSt + rr + lg*8);
        bf16x8 k3 = *(const bf16x8*)(KSt + rr + 32 + lg*8);
        s[fn] = MFMA16(aqw[0], k0, s[fn]);
        s[fn] = MFMA16(aqw[1], k1, s[fn]);
        s[fn] = MFMA16(aqs[0], k2, s[fn]);
        s[fn] = MFMA16(aqs[1], k3, s[fn]);
      }
      #pragma unroll
      for (int fn = 0; fn < 4; fn++){
        #pragma unroll
        for (int r = 0; r < 4; r++){
          int k = kt*64 + fn*16 + li;
          int q = q0 + lg*4 + r;
          float pp = (k <= q) ? __expf(s[fn][r] * rscale) * rinv[r] : 0.f;
          pt[(lg*4 + r)*72 + fn*16 + li] = f2bf(pp);
        }
      }
      asm volatile("s_waitcnt lgkmcnt(0)" ::: "memory");
      __builtin_amdgcn_sched_barrier(0);
      bf16x8 af0 = *(const bf16x8*)(pt + li*72 + lg*8);
      bf16x8 af1 = *(const bf16x8*)(pt + li*72 + 32 + lg*8);
      ushort8_t u0 = __builtin_bit_cast(ushort8_t, af0);
      ushort8_t u1 = __builtin_bit_cast(ushort8_t, af1);
      *(float4*)(abase + lg*8)          = (float4){bf2f(u0[0]),bf2f(u0[1]),bf2f(u0[2]),bf2f(u0[3])};
      *(float4*)(abase + lg*8 + 4)      = (float4){bf2f(u0[4]),bf2f(u0[5]),bf2f(u0[6]),bf2f(u0[7])};
      *(float4*)(abase + 32 + lg*8)     = (float4){bf2f(u1[0]),bf2f(u1[1]),bf2f(u1[2]),bf2f(u1[3])};
      *(float4*)(abase + 32 + lg*8 + 4) = (float4){bf2f(u1[4]),bf2f(u1[5]),bf2f(u1[6]),bf2f(u1[7])};
      #pragma unroll
      for (int fn = 0; fn < 4; fn++){
        int rr = (fn*16 + li)*72;
        bf16x8 v0 = *(const bf16x8*)(VTt + rr + lg*8);
        bf16x8 v1 = *(const bf16x8*)(VTt + rr + 32 + lg*8);
        c[fn] = MFMA16(af0, v0, c[fn]);
        c[fn] = MFMA16(af1, v1, c[fn]);
      }
    } else {
      float4 z = {0.f, 0.f, 0.f, 0.f};
      *(float4*)(abase + lg*8)          = z;
      *(float4*)(abase + lg*8 + 4)      = z;
      *(float4*)(abase + 32 + lg*8)     = z;
      *(float4*)(abase + 32 + lg*8 + 4) = z;
    }
    if (kt < maxkt){
      int nb = buf ^ 1;
      *(uint4*)(SL +         nb*4608 + srow*72 + scb*8) = rkw;
      *(uint4*)(SL +  9216 + nb*4608 + srow*72 + scb*8) = rks;
      *(uint4*)(SL + 18432 + nb*4608 + srow*72 + scb*8) = rvt;
    }
  }

  // ctx write: D layout row=(l>>4)*4+r, col=l&15  (re-read by gemm_out -> keep cached)
  #pragma unroll
  for (int fn = 0; fn < 4; fn++){
    #pragma unroll
    for (int r = 0; r < 4; r++){
      int q = q0 + lg*4 + r;
      int d = fn*16 + li;
      Ctx[(size_t)(b*1024 + q)*1024 + h*64 + d] = f2bf(c[fn][r]);
    }
  }
}

// ---------------- host launch ----------------
extern "C" void kernel_launch(void* const* d_in, const int* in_sizes, int n_in,
                              void* d_out, int out_size, void* d_ws, size_t ws_size,
                              hipStream_t stream)
{
  (void)in_sizes; (void)n_in; (void)out_size; (void)ws_size;
  const float* word = (const float*)d_in[0];
  const float* spk  = (const float*)d_in[1];
  const float* qww  = (const float*)d_in[3];
  const float* qwb  = (const float*)d_in[4];
  const float* kww  = (const float*)d_in[5];
  const float* kwb  = (const float*)d_in[6];
  const float* qsw  = (const float*)d_in[7];
  const float* qsb  = (const float*)d_in[8];
  const float* ksw  = (const float*)d_in[9];
  const float* ksb  = (const float*)d_in[10];
  const float* vw   = (const float*)d_in[11];
  const float* vb   = (const float*)d_in[12];
  const float* outw = (const float*)d_in[13];
  const float* outb = (const float*)d_in[14];
  const float* gamma= (const float*)d_in[15];
  const float* beta = (const float*)d_in[16];

  unsigned short* U = (unsigned short*)d_ws;
  unsigned short* XW    = U + E_XW;
  unsigned short* XS    = U + E_XS;
  unsigned short* WWORD = U + E_WWORD;
  unsigned short* WSPK  = U + E_WSPK;
  unsigned short* WOUT  = U + E_WOUT;
  unsigned short* PWORD = U + E_PWORD;
  unsigned short* PSPK  = U + E_PSPK;
  unsigned short* VT    = U + E_VT;
  unsigned short* CTX   = U + E_CTX;
  float* FB = (float*)(U + E_END);
  float* TS = FB + 5120;
  float* TC = TS + 32768;

  float* outp = (float*)d_out;
  float* attn = outp + (size_t)2*1024*1024;

  convert_all<<<4096, 256, 0, stream>>>(word, spk, qww, kww, vw, qsw, ksw, outw,
                                        qwb, kwb, vb, qsb, ksb, U, FB);
  gemm_qkv<<<640, 256, 0, stream>>>(XW, WWORD, XS, WSPK, FB, PWORD, PSPK);
  postproc<<<4608, 256, 0, stream>>>(PWORD, PSPK, gamma, beta, TS, TC, VT);
  attn_fused<<<256, 512, 0, stream>>>(PWORD, PSPK, VT, attn, CTX);
  gemm_out<<<256, 256, 0, stream>>>(CTX, WOUT, outb, outp);
}